// Round 13
// baseline (745.347 us; speedup 1.0000x reference)
//
#include <hip/hip_runtime.h>

#define PD 64
#define BIN_C 6144   // edges staged per block in k_bin (48KB LDS)
#define RB 512       // nodes per bucket (log2 = 9)

typedef __attribute__((ext_vector_type(8))) short s8v;   // 8 bf16 (4 VGPRs)
typedef __attribute__((ext_vector_type(4))) float f4v;   // MFMA accumulator
#define MFMA(a, b, c) __builtin_amdgcn_mfma_f32_16x16x32_bf16(a, b, c, 0, 0, 0)

__device__ __forceinline__ unsigned short f2bf(float f) {   // RNE float->bf16
  unsigned u = __float_as_uint(f);
  return (unsigned short)((u + 0x7FFFu + ((u >> 16) & 1u)) >> 16);
}
__device__ __forceinline__ float bf2f(unsigned short h) {
  return __uint_as_float(((unsigned)h) << 16);
}
union U8 { unsigned int w[4]; s8v v; };

// ---------------- phase 1: bin edges by bucket (locality-preserving) ----------------
__global__ __launch_bounds__(256) void k_bin(const int* __restrict__ ei,
    const float* __restrict__ w, uint2* __restrict__ bkt_in, uint2* __restrict__ bkt_out,
    int* __restrict__ bcnt, int E, int K, int cap) {
  __shared__ uint2 staged[BIN_C];
  __shared__ unsigned short bin16[BIN_C];
  __shared__ int cnt[256], base[257], off[256];
  int dir = blockIdx.y;
  const int* __restrict__ keys = dir ? ei : ei + E;
  const int* __restrict__ vals = dir ? ei + E : ei;
  uint2* __restrict__ bdst = dir ? bkt_out : bkt_in;
  int tid = threadIdx.x;
  int e0 = blockIdx.x * BIN_C;
  int count = min(BIN_C, E - e0);
  cnt[tid] = 0;
  __syncthreads();
  for (int i = tid; i < count; i += 256) {
    int b = keys[e0 + i] >> 9;
    bin16[i] = (unsigned short)b;
    atomicAdd(&cnt[b], 1);
  }
  __syncthreads();
  int v = cnt[tid];
  off[tid] = v;
  __syncthreads();
  for (int o = 1; o < 256; o <<= 1) {
    int t = (tid >= o) ? off[tid - o] : 0;
    __syncthreads();
    off[tid] += t;
    __syncthreads();
  }
  base[tid] = off[tid] - v;
  if (tid == 255) base[256] = off[255];
  __syncthreads();
  off[tid] = 0;
  __syncthreads();
  for (int i = tid; i < count; i += 256) {
    int e = e0 + i;
    int k = keys[e];
    int b = bin16[i];
    int l = k & (RB - 1);
    unsigned int packed = ((unsigned int)vals[e] << 9) | (unsigned int)l;
    int p = base[b] + atomicAdd(&off[b], 1);
    staged[p] = make_uint2(packed, __float_as_uint(w[e]));
  }
  __syncthreads();
  if (tid < K) {
    int c = cnt[tid];
    off[tid] = c > 0 ? atomicAdd(&bcnt[dir * K + tid], c) : 0;
  }
  __syncthreads();
  for (int i = tid; i < count; i += 256) {
    int lo = 0, hi = K;
    while (hi - lo > 1) { int mid = (lo + hi) >> 1; if (base[mid] <= i) lo = mid; else hi = mid; }
    int b = lo;
    int rel = off[b] + (i - base[b]);
    if (rel < cap) bdst[(size_t)b * cap + rel] = staged[i];
  }
}

// ---------------- phase 2: per-bucket local CSR ----------------
__global__ __launch_bounds__(256) void k_bucket(
    const uint2* __restrict__ bkt_in, const uint2* __restrict__ bkt_out,
    const int* __restrict__ bcnt,
    int* __restrict__ beg_in, int* __restrict__ end_in,
    int* __restrict__ beg_out, int* __restrict__ end_out,
    float* __restrict__ sw_in, float* __restrict__ sw_out,
    int* __restrict__ col_in, int* __restrict__ col_out,
    int cap, int N, int K) {
  __shared__ int deg[RB], pos[RB], off[RB];
  __shared__ float swl[RB];
  __shared__ int ps[256];
  int b = blockIdx.x, dir = blockIdx.y, tid = threadIdx.x;
  const uint2* __restrict__ bkt = (dir ? bkt_out : bkt_in) + (size_t)b * cap;
  int* __restrict__ beg = dir ? beg_out : beg_in;
  int* __restrict__ end = dir ? end_out : end_in;
  float* __restrict__ swg = dir ? sw_out : sw_in;
  int* __restrict__ col = dir ? col_out : col_in;
  int len = bcnt[dir * K + b];
  if (len > cap) len = cap;
  deg[tid] = 0; deg[tid + 256] = 0;
  swl[tid] = 0.f; swl[tid + 256] = 0.f;
  __syncthreads();
  for (int i = tid; i < len; i += 256) {
    uint2 u = bkt[i];
    int l = u.x & (RB - 1);
    atomicAdd(&deg[l], 1);
    atomicAdd(&swl[l], __uint_as_float(u.y));
  }
  __syncthreads();
  int a0 = deg[2 * tid], a1 = deg[2 * tid + 1];
  ps[tid] = a0 + a1;
  __syncthreads();
  for (int o = 1; o < 256; o <<= 1) {
    int t = (tid >= o) ? ps[tid - o] : 0;
    __syncthreads();
    ps[tid] += t;
    __syncthreads();
  }
  int ex = ps[tid] - (a0 + a1);
  pos[2 * tid] = ex;
  pos[2 * tid + 1] = ex + a0;
  off[tid] = 0; off[tid + 256] = 0;
  __syncthreads();
  int base_node = b << 9;
  size_t colbase = (size_t)b * cap;
  for (int l = tid; l < RB; l += 256) {
    int g = base_node + l;
    if (g < N) {
      beg[g] = (int)(colbase + pos[l]);
      end[g] = (int)(colbase + pos[l] + deg[l]);
      swg[g] = swl[l];
    }
  }
  __syncthreads();
  for (int i = tid; i < len; i += 256) {
    uint2 u = bkt[i];
    int l = u.x & (RB - 1);
    int s = (int)(u.x >> 9);
    int p = pos[l] + atomicAdd(&off[l], 1);
    col[colbase + p] = s;
  }
}

// ---------------- weight folding + MFMA fragment packing ----------------
__global__ void k_wprep(const float* __restrict__ W1, const float* __restrict__ W2,
                        const float* __restrict__ W3, const float* __restrict__ W4,
                        const float* __restrict__ Wc1, const float* __restrict__ Wc2,
                        const float* __restrict__ Wcomp, const float* __restrict__ W7,
                        float* c1, float* c3, unsigned short* fragMt,
                        unsigned short* fragC2, unsigned short* fragCmp, float* W7t) {
  int t = blockIdx.x;
  int tid = threadIdx.x;
  __shared__ float r4[64], v3[64];
  __shared__ float sM[4096];
  if (tid < 64) r4[tid] = fmaxf(W4[t * 64 + tid], 0.f);
  __syncthreads();
  if (tid < 64) {
    float s = 0.f;
    for (int k = 0; k < 64; ++k) s += W3[t * 4096 + tid * 64 + k] * r4[k];
    v3[tid] = s;
    float s1 = 0.f;
    for (int k = 0; k < 64; ++k) s1 += Wc1[t * 12288 + tid * 192 + k] * W1[t * 64 + k];
    c1[t * 64 + tid] = s1;
  }
  __syncthreads();
  if (tid < 64) {
    float s = 0.f;
    for (int k = 0; k < 64; ++k) s += Wc1[t * 12288 + tid * 192 + 128 + k] * v3[k];
    c3[t * 64 + tid] = s;
  }
  for (int idx = tid; idx < 4096; idx += 256) {
    int j = idx >> 6, p = idx & 63;
    float s = 0.f;
    for (int k = 0; k < 64; ++k)
      s += Wc1[t * 12288 + p * 192 + 64 + k] * W2[t * 4096 + k * 64 + j];
    sM[j * 64 + p] = s;   // B_Mt[j][p]
  }
  __syncthreads();
  for (int idx = tid; idx < 512; idx += 256) {
    int c = idx >> 8, n0 = (idx >> 6) & 3, lane = idx & 63;
    int kb = c * 32 + ((lane >> 4) << 3), nn = n0 * 16 + (lane & 15);
    int off = ((c * 4 + n0) * 64 + lane) * 8;
    unsigned short* mh = fragMt + (size_t)t * 8192 + off;
    unsigned short* ch = fragC2 + (size_t)t * 8192 + off;
    for (int e = 0; e < 8; ++e) {
      float w = sM[(kb + e) * 64 + nn];
      unsigned short h = f2bf(w);
      mh[e] = h; mh[4096 + e] = f2bf(w - bf2f(h));
      float w2 = Wc2[t * 4096 + nn * 64 + (kb + e)];   // B_C2[j][p] = Wc2[p][j]
      unsigned short h2 = f2bf(w2);
      ch[e] = h2; ch[4096 + e] = f2bf(w2 - bf2f(h2));
    }
  }
  if (t == 0) {
    for (int idx = tid; idx < 1024; idx += 256) {
      int c = idx >> 8, n0 = (idx >> 6) & 3, lane = idx & 63;
      int kb = c * 32 + ((lane >> 4) << 3), nn = n0 * 16 + (lane & 15);
      int off = ((c * 4 + n0) * 64 + lane) * 8;
      for (int e = 0; e < 8; ++e) {
        float w = Wcomp[nn * 128 + kb + e];             // B_cmp[j][p] = Wcomp[p][j]
        unsigned short h = f2bf(w);
        fragCmp[off + e] = h; fragCmp[8192 + off + e] = f2bf(w - bf2f(h));
      }
    }
    for (int idx = tid; idx < 4096; idx += 256) {
      int j = idx >> 6, p = idx & 63;
      W7t[idx] = W7[p * 64 + j];
    }
  }
}

// ---------------- edge aggregation: feature-PAIR lanes, edge-parity halves ----------
__global__ __launch_bounds__(256) void k_agg(
    const int* __restrict__ beg_in, const int* __restrict__ end_in,
    const int* __restrict__ col_in,
    const int* __restrict__ beg_out, const int* __restrict__ end_out,
    const int* __restrict__ col_out,
    const unsigned short* __restrict__ mub, unsigned short* __restrict__ aggb_in,
    unsigned short* __restrict__ aggb_out, int n) {
  int wave = (blockIdx.x * blockDim.x + threadIdx.x) >> 6;
  int lane = threadIdx.x & 63;
  int half = lane >> 5;          // 0: even-index edges, 1: odd-index edges
  int fp = lane & 31;            // feature-pair index
  if (wave >= n) return;
  const unsigned int* __restrict__ mrow = (const unsigned int*)mub;
#pragma unroll
  for (int dir = 0; dir < 2; ++dir) {
    const int* __restrict__ bega = dir ? beg_out : beg_in;
    const int* __restrict__ enda = dir ? end_out : end_in;
    const int* __restrict__ col = dir ? col_out : col_in;
    unsigned short* __restrict__ aggb = dir ? aggb_out : aggb_in;
    int b = bega[wave], e = enda[wave];
    int cnt = e - b;
    int myn = (cnt > half) ? ((cnt - half + 1) >> 1) : 0;   // my half's edge count
    float ax[4], ay[4];
#pragma unroll
    for (int u = 0; u < 4; ++u) { ax[u] = 0.f; ay[u] = 0.f; }
    int base = b + half;
    int i = 0;
    int bulk = myn & ~7;
    for (; i < bulk; i += 8) {            // bulk: no masks
      int idx[8];
#pragma unroll
      for (int u = 0; u < 8; ++u) idx[u] = col[base + 2 * (i + u)];
      unsigned int v[8];
#pragma unroll
      for (int u = 0; u < 8; ++u) v[u] = mrow[((size_t)idx[u] << 5) + fp];
#pragma unroll
      for (int u = 0; u < 8; ++u) {
        ax[u & 3] += __uint_as_float(v[u] << 16);
        ay[u & 3] += __uint_as_float(v[u] & 0xFFFF0000u);
      }
    }
    if (i < myn) {                        // single masked tail group
      int last = myn - 1;
      int idx[8];
      float msk[8];
#pragma unroll
      for (int u = 0; u < 8; ++u) {
        int kk = i + u;
        idx[u] = col[base + 2 * (kk <= last ? kk : last)];
        msk[u] = (kk <= last) ? 1.f : 0.f;
      }
      unsigned int v[8];
#pragma unroll
      for (int u = 0; u < 8; ++u) v[u] = mrow[((size_t)idx[u] << 5) + fp];
#pragma unroll
      for (int u = 0; u < 8; ++u) {
        ax[u & 3] = fmaf(msk[u], __uint_as_float(v[u] << 16), ax[u & 3]);
        ay[u & 3] = fmaf(msk[u], __uint_as_float(v[u] & 0xFFFF0000u), ay[u & 3]);
      }
    }
    float sx = (ax[0] + ax[1]) + (ax[2] + ax[3]);
    float sy = (ay[0] + ay[1]) + (ay[2] + ay[3]);
    sx += __shfl_xor(sx, 32);             // merge even/odd halves
    sy += __shfl_xor(sy, 32);
    unsigned short h0 = f2bf(sx), h1 = f2bf(sy);
    unsigned short l0 = f2bf(sx - bf2f(h0)), l1 = f2bf(sy - bf2f(h1));
    unsigned int pack = half ? ((unsigned)l0 | ((unsigned)l1 << 16))
                             : ((unsigned)h0 | ((unsigned)h1 << 16));
    ((unsigned int*)aggb)[(size_t)wave * 64 + lane] = pack;   // coalesced 256B
  }
}

// ---------------- MFMA k_node helpers (M=2: wave owns 32 nodes) ----------------
__device__ __forceinline__ void load_alds(const unsigned int* qp, s8v& ah, s8v& al) {
  uint4 qa = *(const uint4*)qp;
  uint4 qb = *(const uint4*)(qp + 4);
  U8 uh, ul;
  uh.w[0] = (qa.x & 0xFFFFu) | (qa.y << 16);
  uh.w[1] = (qa.z & 0xFFFFu) | (qa.w << 16);
  uh.w[2] = (qb.x & 0xFFFFu) | (qb.y << 16);
  uh.w[3] = (qb.z & 0xFFFFu) | (qb.w << 16);
  ul.w[0] = (qa.x >> 16) | (qa.y & 0xFFFF0000u);
  ul.w[1] = (qa.z >> 16) | (qa.w & 0xFFFF0000u);
  ul.w[2] = (qb.x >> 16) | (qb.y & 0xFFFF0000u);
  ul.w[3] = (qb.z >> 16) | (qb.w & 0xFFFF0000u);
  ah = uh.v;
  al = ul.v;
}

__device__ __forceinline__ void gemm_lds(const unsigned int (*zhl)[76],
                                         const unsigned short* __restrict__ fB,
                                         int loOff, int lane, f4v acc[2][4]) {
  int lrow = lane & 15, lgrp = lane >> 4;
#pragma unroll
  for (int kc = 0; kc < 2; ++kc) {
    s8v Ah[2], Al[2];
#pragma unroll
    for (int m = 0; m < 2; ++m)
      load_alds(&zhl[m * 16 + lrow][kc * 32 + lgrp * 8], Ah[m], Al[m]);
#pragma unroll
    for (int nn = 0; nn < 4; ++nn) {
      const unsigned short* bp = fB + ((kc * 4 + nn) * 64 + lane) * 8;
      s8v Bh = *(const s8v*)bp;
      s8v Bl = *(const s8v*)(bp + loOff);
#pragma unroll
      for (int m = 0; m < 2; ++m) {
        acc[m][nn] = MFMA(Ah[m], Bh, acc[m][nn]);
        acc[m][nn] = MFMA(Al[m], Bh, acc[m][nn]);
        acc[m][nn] = MFMA(Ah[m], Bl, acc[m][nn]);
      }
    }
  }
}

__device__ __forceinline__ void store_zhl(unsigned int (*zhl)[76], const f4v acc[2][4],
                                          int lane) {
  int lrow = lane & 15, lgrp = lane >> 4;
#pragma unroll
  for (int m = 0; m < 2; ++m)
#pragma unroll
    for (int nn = 0; nn < 4; ++nn)
#pragma unroll
      for (int r = 0; r < 4; ++r) {
        float v = fmaxf(acc[m][nn][r], 0.f);
        unsigned short h = f2bf(v);
        unsigned short l = f2bf(v - bf2f(h));
        zhl[m * 16 + lgrp * 4 + r][nn * 16 + lrow] = (unsigned)h | ((unsigned)l << 16);
      }
}

// ---------------- fused per-node GEMM chain on the MATRIX pipe ----------------
// 1 wave per 32 nodes (M=2): acc[2][4]+accO[2][4]=64 f32 live -> no spills at the
// 128-VGPR cap; 9.7KB LDS tile -> ~16 blocks/CU; grid 2x for latency hiding.
__global__ __launch_bounds__(64, 4) void k_node(
    const float* __restrict__ x, const float* __restrict__ sw_in,
    const float* __restrict__ sw_out, const unsigned short* __restrict__ aggb_in,
    const unsigned short* __restrict__ aggb_out, const float* __restrict__ c1g,
    const float* __restrict__ c3g, const unsigned short* __restrict__ fragMt,
    const unsigned short* __restrict__ fragC2, const unsigned short* __restrict__ fragCmp,
    float* __restrict__ mu, unsigned short* __restrict__ mub,
    int n, int t, int haveAgg, int last) {
  __shared__ unsigned int zhl[32][76];
  int lane = threadIdx.x;
  int lrow = lane & 15, lgrp = lane >> 4;
  int node0 = blockIdx.x * 32;
  const unsigned short* fMt = fragMt + (size_t)t * 8192;
  const unsigned short* fC2 = fragC2 + (size_t)t * 8192;
  float c1v[4], c3v[4];
#pragma unroll
  for (int nn = 0; nn < 4; ++nn) {
    c1v[nn] = c1g[t * 64 + nn * 16 + lrow];
    c3v[nn] = c3g[t * 64 + nn * 16 + lrow];
  }
  f4v accO[2][4];
#pragma unroll
  for (int m = 0; m < 2; ++m)
#pragma unroll
    for (int nn = 0; nn < 4; ++nn) accO[m][nn] = (f4v){0.f, 0.f, 0.f, 0.f};

#pragma unroll 1
  for (int dir = 0; dir < 2; ++dir) {
    const unsigned short* aggb = dir ? aggb_out : aggb_in;
    const float* sw = dir ? sw_out : sw_in;
    f4v acc[2][4];
#pragma unroll
    for (int m = 0; m < 2; ++m)
#pragma unroll
      for (int r = 0; r < 4; ++r) {
        int nd = node0 + m * 16 + lgrp * 4 + r;
        nd = nd < n ? nd : n - 1;
        float xl = x[nd], sl = sw[nd];
#pragma unroll
        for (int nn = 0; nn < 4; ++nn) acc[m][nn][r] = xl * c1v[nn] + sl * c3v[nn];
      }
    if (haveAgg) {   // z += agg @ Mt
#pragma unroll
      for (int kc = 0; kc < 2; ++kc) {
        s8v Ah[2], Al[2];
#pragma unroll
        for (int m = 0; m < 2; ++m) {
          const unsigned short* ap =
              aggb + (size_t)(node0 + m * 16 + lrow) * 128 + kc * 32 + lgrp * 8;
          Ah[m] = *(const s8v*)ap;
          Al[m] = *(const s8v*)(ap + 64);
        }
#pragma unroll
        for (int nn = 0; nn < 4; ++nn) {
          const unsigned short* bp = fMt + ((kc * 4 + nn) * 64 + lane) * 8;
          s8v Bh = *(const s8v*)bp;
          s8v Bl = *(const s8v*)(bp + 4096);
#pragma unroll
          for (int m = 0; m < 2; ++m) {
            acc[m][nn] = MFMA(Ah[m], Bh, acc[m][nn]);
            acc[m][nn] = MFMA(Al[m], Bh, acc[m][nn]);
            acc[m][nn] = MFMA(Ah[m], Bl, acc[m][nn]);
          }
        }
      }
    }
    store_zhl(zhl, acc, lane);                 // z = relu(...)
#pragma unroll
    for (int m = 0; m < 2; ++m)
#pragma unroll
      for (int nn = 0; nn < 4; ++nn) acc[m][nn] = (f4v){0.f, 0.f, 0.f, 0.f};
    gemm_lds(zhl, fC2, 4096, lane, acc);       // m = relu(z @ C2)
    store_zhl(zhl, acc, lane);
    gemm_lds(zhl, fragCmp + dir * 4096, 8192, lane, accO);  // o += m @ Cmp[dir]
  }
  if (last) {
#pragma unroll
    for (int m = 0; m < 2; ++m)
#pragma unroll
      for (int r = 0; r < 4; ++r) {
        int nd = node0 + m * 16 + lgrp * 4 + r;
        if (nd < n) {
#pragma unroll
          for (int nn = 0; nn < 4; ++nn)
            mu[(size_t)nd * 64 + nn * 16 + lrow] = fmaxf(accO[m][nn][r], 0.f);
        }
      }
  } else {
#pragma unroll
    for (int m = 0; m < 2; ++m)
#pragma unroll
      for (int r = 0; r < 4; ++r) {
        int nd = node0 + m * 16 + lgrp * 4 + r;
        if (nd < n) {
#pragma unroll
          for (int nn = 0; nn < 4; ++nn)
            mub[(size_t)nd * 64 + nn * 16 + lrow] = f2bf(fmaxf(accO[m][nn][r], 0.f));
        }
      }
  }
}

// ---------------- pooling: wave per 64-node chunk, ILP-8 fast path ----------------
__global__ __launch_bounds__(256) void k_pool(
    const float* __restrict__ mu, const int* __restrict__ batch,
    float* __restrict__ pool, int n) {
  int gw = (blockIdx.x * blockDim.x + threadIdx.x) >> 6;
  int lane = threadIdx.x & 63;
  int start = gw * 64;
  if (start >= n) return;
  int end = min(start + 64, n);
  int b0 = batch[start];
  if (b0 == batch[end - 1] && end - start == 64) {
    float a[8];
#pragma unroll
    for (int u = 0; u < 8; ++u) a[u] = 0.f;
#pragma unroll
    for (int g = 0; g < 8; ++g) {
#pragma unroll
      for (int u = 0; u < 8; ++u)
        a[u] += mu[(size_t)(start + g * 8 + u) * 64 + lane];   // 8 independent chains
    }
    float s = ((a[0] + a[1]) + (a[2] + a[3])) + ((a[4] + a[5]) + (a[6] + a[7]));
    atomicAdd(&pool[b0 * 64 + lane], s);
  } else {
    int cur = b0;
    float acc = 0.f;
    for (int i = start; i < end; ++i) {
      int b = batch[i];
      if (b != cur) {
        atomicAdd(&pool[cur * 64 + lane], acc);
        acc = 0.f;
        cur = b;
      }
      acc += mu[(size_t)i * 64 + lane];
    }
    atomicAdd(&pool[cur * 64 + lane], acc);
  }
}

__global__ void k_poolw6(const float* __restrict__ pool, const float* __restrict__ W6,
                         float* __restrict__ out) {
  int idx = blockIdx.x * blockDim.x + threadIdx.x;  // < 4096
  int g = idx >> 6, p = idx & 63;
  float s = 0.f;
  for (int k = 0; k < 64; ++k) s += pool[g * 64 + k] * W6[p * 64 + k];
  out[idx] = s;
}

// ---------------- head ----------------
__global__ __launch_bounds__(256) void k_final(
    const float* __restrict__ mu, const int* __restrict__ batch,
    const float* __restrict__ poolw6, const float* __restrict__ W7t,
    const float* __restrict__ W5, float* __restrict__ out, int n) {
  __shared__ float S[4][64];
  int tid = threadIdx.x, lane = tid & 63, w = tid >> 6;
  int node = blockIdx.x * 4 + w;
  if (node >= n) return;
  float mv = mu[(size_t)node * 64 + lane];
  S[w][lane] = mv;
  __builtin_amdgcn_wave_barrier();
  int g = batch[node];
  float t1 = fmaxf(poolw6[g * 64 + lane], 0.f);
  float acc = 0.f;
#pragma unroll 8
  for (int j = 0; j < 64; ++j) acc = fmaf(S[w][j], W7t[j * 64 + lane], acc);
  float t2 = fmaxf(acc, 0.f);
  float val = W5[lane] * t1 + W5[64 + lane] * t2;
  for (int off = 32; off > 0; off >>= 1) val += __shfl_down(val, off);
  if (lane == 0) out[node] = fmaxf(val, 0.f);
}

extern "C" void kernel_launch(void* const* d_in, const int* in_sizes, int n_in,
                              void* d_out, int out_size, void* d_ws, size_t ws_size,
                              hipStream_t stream) {
  const float* x = (const float*)d_in[0];
  const float* weight = (const float*)d_in[1];
  const int* ei = (const int*)d_in[2];
  const int* batch = (const int*)d_in[3];
  const float* W1 = (const float*)d_in[4];
  const float* W2 = (const float*)d_in[5];
  const float* W3 = (const float*)d_in[6];
  const float* W4 = (const float*)d_in[7];
  const float* Wc1 = (const float*)d_in[8];
  const float* Wc2 = (const float*)d_in[9];
  const float* Wcomp = (const float*)d_in[10];
  const float* W5 = (const float*)d_in[11];
  const float* W6 = (const float*)d_in[12];
  const float* W7 = (const float*)d_in[13];
  float* out = (float*)d_out;
  int N = in_sizes[0];
  int E = in_sizes[1];
  int T = in_sizes[4] / 64;

  int K = (N + RB - 1) / RB;
  int cap = E / K + E / (4 * K) + 1024;
  int Nw = ((N + 63) / 64) * 64;

  char* ws = (char*)d_ws;
  size_t off = 0;
  auto alloc = [&](size_t bytes) {
    size_t o = off;
    off += (bytes + 255) & ~(size_t)255;
    return o;
  };
  // zeroed region
  size_t o_bcnt = alloc((size_t)2 * K * 4);
  size_t o_pool = alloc(4096 * 4);
  size_t zero_end = off;
  size_t o_beg_in = alloc((size_t)N * 4);
  size_t o_end_in = alloc((size_t)N * 4);
  size_t o_beg_out = alloc((size_t)N * 4);
  size_t o_end_out = alloc((size_t)N * 4);
  size_t o_sw_in = alloc((size_t)N * 4);
  size_t o_sw_out = alloc((size_t)N * 4);
  size_t o_col_in = alloc((size_t)K * cap * 4);
  size_t o_col_out = alloc((size_t)K * cap * 4);
  size_t o_mu = alloc((size_t)Nw * 64 * 4);
  size_t o_mub = alloc((size_t)Nw * 64 * 2);   // bf16-hi mu for the gather
  size_t aggBytes = (size_t)Nw * 128 * 2;      // bf16 hi+lo planes
  size_t bktBytes = (size_t)K * cap * 8;
  size_t big = aggBytes > bktBytes ? aggBytes : bktBytes;
  size_t o_aggb_in = alloc(big);   // aliased: bkt_in during build
  size_t o_aggb_out = alloc(big);  // aliased: bkt_out during build
  size_t o_c1 = alloc(4 * 64 * 4);
  size_t o_c3 = alloc(4 * 64 * 4);
  size_t o_fragMt = alloc((size_t)4 * 8192 * 2);
  size_t o_fragC2 = alloc((size_t)4 * 8192 * 2);
  size_t o_fragCmp = alloc((size_t)16384 * 2);
  size_t o_W7t = alloc(4096 * 4);
  size_t o_poolw6 = alloc(4096 * 4);
  (void)ws_size; (void)n_in; (void)out_size;

  hipMemsetAsync(ws, 0, zero_end, stream);

  dim3 gBin((E + BIN_C - 1) / BIN_C, 2);
  k_bin<<<gBin, 256, 0, stream>>>(ei, weight, (uint2*)(ws + o_aggb_in),
                                  (uint2*)(ws + o_aggb_out), (int*)(ws + o_bcnt),
                                  E, K, cap);
  dim3 gBkt(K, 2);
  k_bucket<<<gBkt, 256, 0, stream>>>((uint2*)(ws + o_aggb_in), (uint2*)(ws + o_aggb_out),
                                     (int*)(ws + o_bcnt),
                                     (int*)(ws + o_beg_in), (int*)(ws + o_end_in),
                                     (int*)(ws + o_beg_out), (int*)(ws + o_end_out),
                                     (float*)(ws + o_sw_in), (float*)(ws + o_sw_out),
                                     (int*)(ws + o_col_in), (int*)(ws + o_col_out),
                                     cap, N, K);
  k_wprep<<<T, 256, 0, stream>>>(W1, W2, W3, W4, Wc1, Wc2, Wcomp, W7,
                                 (float*)(ws + o_c1), (float*)(ws + o_c3),
                                 (unsigned short*)(ws + o_fragMt),
                                 (unsigned short*)(ws + o_fragC2),
                                 (unsigned short*)(ws + o_fragCmp),
                                 (float*)(ws + o_W7t));

  int gN4 = (N + 3) / 4;
  int gNode = Nw / 32;
  for (int t = 0; t < T; ++t) {
    if (t > 0)
      k_agg<<<gN4, 256, 0, stream>>>((int*)(ws + o_beg_in), (int*)(ws + o_end_in),
                                     (int*)(ws + o_col_in),
                                     (int*)(ws + o_beg_out), (int*)(ws + o_end_out),
                                     (int*)(ws + o_col_out),
                                     (unsigned short*)(ws + o_mub),
                                     (unsigned short*)(ws + o_aggb_in),
                                     (unsigned short*)(ws + o_aggb_out), N);
    k_node<<<gNode, 64, 0, stream>>>(x, (float*)(ws + o_sw_in), (float*)(ws + o_sw_out),
                                     (unsigned short*)(ws + o_aggb_in),
                                     (unsigned short*)(ws + o_aggb_out),
                                     (float*)(ws + o_c1), (float*)(ws + o_c3),
                                     (unsigned short*)(ws + o_fragMt),
                                     (unsigned short*)(ws + o_fragC2),
                                     (unsigned short*)(ws + o_fragCmp),
                                     (float*)(ws + o_mu),
                                     (unsigned short*)(ws + o_mub),
                                     N, t, t > 0 ? 1 : 0, t == T - 1 ? 1 : 0);
  }
  int gPool = ((N + 63) / 64 + 3) / 4;
  k_pool<<<gPool, 256, 0, stream>>>((float*)(ws + o_mu), batch, (float*)(ws + o_pool), N);
  k_poolw6<<<16, 256, 0, stream>>>((float*)(ws + o_pool), W6, (float*)(ws + o_poolw6));
  k_final<<<gN4, 256, 0, stream>>>((float*)(ws + o_mu), batch, (float*)(ws + o_poolw6),
                                   (float*)(ws + o_W7t), W5, out, N);
}

// Round 14
// 587.430 us; speedup vs baseline: 1.2688x; 1.2688x over previous
//
#include <hip/hip_runtime.h>

#define PD 64
#define BIN_C 6144   // edges staged per block in k_bin (48KB LDS)
#define RB 512       // nodes per bucket (log2 = 9)

typedef __attribute__((ext_vector_type(8))) short s8v;   // 8 bf16 (4 VGPRs)
typedef __attribute__((ext_vector_type(4))) float f4v;   // MFMA accumulator
#define MFMA(a, b, c) __builtin_amdgcn_mfma_f32_16x16x32_bf16(a, b, c, 0, 0, 0)

__device__ __forceinline__ unsigned short f2bf(float f) {   // RNE float->bf16
  unsigned u = __float_as_uint(f);
  return (unsigned short)((u + 0x7FFFu + ((u >> 16) & 1u)) >> 16);
}
__device__ __forceinline__ float bf2f(unsigned short h) {
  return __uint_as_float(((unsigned)h) << 16);
}
union U8 { unsigned int w[4]; s8v v; };

// ---------------- phase 1: bin edges by bucket (locality-preserving) ----------------
__global__ __launch_bounds__(256) void k_bin(const int* __restrict__ ei,
    const float* __restrict__ w, uint2* __restrict__ bkt_in, uint2* __restrict__ bkt_out,
    int* __restrict__ bcnt, int E, int K, int cap) {
  __shared__ uint2 staged[BIN_C];
  __shared__ unsigned short bin16[BIN_C];
  __shared__ int cnt[256], base[257], off[256];
  int dir = blockIdx.y;
  const int* __restrict__ keys = dir ? ei : ei + E;
  const int* __restrict__ vals = dir ? ei + E : ei;
  uint2* __restrict__ bdst = dir ? bkt_out : bkt_in;
  int tid = threadIdx.x;
  int e0 = blockIdx.x * BIN_C;
  int count = min(BIN_C, E - e0);
  cnt[tid] = 0;
  __syncthreads();
  for (int i = tid; i < count; i += 256) {
    int b = keys[e0 + i] >> 9;
    bin16[i] = (unsigned short)b;
    atomicAdd(&cnt[b], 1);
  }
  __syncthreads();
  int v = cnt[tid];
  off[tid] = v;
  __syncthreads();
  for (int o = 1; o < 256; o <<= 1) {
    int t = (tid >= o) ? off[tid - o] : 0;
    __syncthreads();
    off[tid] += t;
    __syncthreads();
  }
  base[tid] = off[tid] - v;
  if (tid == 255) base[256] = off[255];
  __syncthreads();
  off[tid] = 0;
  __syncthreads();
  for (int i = tid; i < count; i += 256) {
    int e = e0 + i;
    int k = keys[e];
    int b = bin16[i];
    int l = k & (RB - 1);
    unsigned int packed = ((unsigned int)vals[e] << 9) | (unsigned int)l;
    int p = base[b] + atomicAdd(&off[b], 1);
    staged[p] = make_uint2(packed, __float_as_uint(w[e]));
  }
  __syncthreads();
  if (tid < K) {
    int c = cnt[tid];
    off[tid] = c > 0 ? atomicAdd(&bcnt[dir * K + tid], c) : 0;
  }
  __syncthreads();
  for (int i = tid; i < count; i += 256) {
    int lo = 0, hi = K;
    while (hi - lo > 1) { int mid = (lo + hi) >> 1; if (base[mid] <= i) lo = mid; else hi = mid; }
    int b = lo;
    int rel = off[b] + (i - base[b]);
    if (rel < cap) bdst[(size_t)b * cap + rel] = staged[i];
  }
}

// ---------------- phase 2: per-bucket local CSR ----------------
__global__ __launch_bounds__(256) void k_bucket(
    const uint2* __restrict__ bkt_in, const uint2* __restrict__ bkt_out,
    const int* __restrict__ bcnt,
    int* __restrict__ beg_in, int* __restrict__ end_in,
    int* __restrict__ beg_out, int* __restrict__ end_out,
    float* __restrict__ sw_in, float* __restrict__ sw_out,
    int* __restrict__ col_in, int* __restrict__ col_out,
    int cap, int N, int K) {
  __shared__ int deg[RB], pos[RB], off[RB];
  __shared__ float swl[RB];
  __shared__ int ps[256];
  int b = blockIdx.x, dir = blockIdx.y, tid = threadIdx.x;
  const uint2* __restrict__ bkt = (dir ? bkt_out : bkt_in) + (size_t)b * cap;
  int* __restrict__ beg = dir ? beg_out : beg_in;
  int* __restrict__ end = dir ? end_out : end_in;
  float* __restrict__ swg = dir ? sw_out : sw_in;
  int* __restrict__ col = dir ? col_out : col_in;
  int len = bcnt[dir * K + b];
  if (len > cap) len = cap;
  deg[tid] = 0; deg[tid + 256] = 0;
  swl[tid] = 0.f; swl[tid + 256] = 0.f;
  __syncthreads();
  for (int i = tid; i < len; i += 256) {
    uint2 u = bkt[i];
    int l = u.x & (RB - 1);
    atomicAdd(&deg[l], 1);
    atomicAdd(&swl[l], __uint_as_float(u.y));
  }
  __syncthreads();
  int a0 = deg[2 * tid], a1 = deg[2 * tid + 1];
  ps[tid] = a0 + a1;
  __syncthreads();
  for (int o = 1; o < 256; o <<= 1) {
    int t = (tid >= o) ? ps[tid - o] : 0;
    __syncthreads();
    ps[tid] += t;
    __syncthreads();
  }
  int ex = ps[tid] - (a0 + a1);
  pos[2 * tid] = ex;
  pos[2 * tid + 1] = ex + a0;
  off[tid] = 0; off[tid + 256] = 0;
  __syncthreads();
  int base_node = b << 9;
  size_t colbase = (size_t)b * cap;
  for (int l = tid; l < RB; l += 256) {
    int g = base_node + l;
    if (g < N) {
      beg[g] = (int)(colbase + pos[l]);
      end[g] = (int)(colbase + pos[l] + deg[l]);
      swg[g] = swl[l];
    }
  }
  __syncthreads();
  for (int i = tid; i < len; i += 256) {
    uint2 u = bkt[i];
    int l = u.x & (RB - 1);
    int s = (int)(u.x >> 9);
    int p = pos[l] + atomicAdd(&off[l], 1);
    col[colbase + p] = s;
  }
}

// ---------------- weight folding + MFMA fragment packing ----------------
__global__ void k_wprep(const float* __restrict__ W1, const float* __restrict__ W2,
                        const float* __restrict__ W3, const float* __restrict__ W4,
                        const float* __restrict__ Wc1, const float* __restrict__ Wc2,
                        const float* __restrict__ Wcomp, const float* __restrict__ W7,
                        float* c1, float* c3, unsigned short* fragMt,
                        unsigned short* fragC2, unsigned short* fragCmp, float* W7t) {
  int t = blockIdx.x;
  int tid = threadIdx.x;
  __shared__ float r4[64], v3[64];
  __shared__ float sM[4096];
  if (tid < 64) r4[tid] = fmaxf(W4[t * 64 + tid], 0.f);
  __syncthreads();
  if (tid < 64) {
    float s = 0.f;
    for (int k = 0; k < 64; ++k) s += W3[t * 4096 + tid * 64 + k] * r4[k];
    v3[tid] = s;
    float s1 = 0.f;
    for (int k = 0; k < 64; ++k) s1 += Wc1[t * 12288 + tid * 192 + k] * W1[t * 64 + k];
    c1[t * 64 + tid] = s1;
  }
  __syncthreads();
  if (tid < 64) {
    float s = 0.f;
    for (int k = 0; k < 64; ++k) s += Wc1[t * 12288 + tid * 192 + 128 + k] * v3[k];
    c3[t * 64 + tid] = s;
  }
  for (int idx = tid; idx < 4096; idx += 256) {
    int j = idx >> 6, p = idx & 63;
    float s = 0.f;
    for (int k = 0; k < 64; ++k)
      s += Wc1[t * 12288 + p * 192 + 64 + k] * W2[t * 4096 + k * 64 + j];
    sM[j * 64 + p] = s;   // B_Mt[j][p]
  }
  __syncthreads();
  for (int idx = tid; idx < 512; idx += 256) {
    int c = idx >> 8, n0 = (idx >> 6) & 3, lane = idx & 63;
    int kb = c * 32 + ((lane >> 4) << 3), nn = n0 * 16 + (lane & 15);
    int off = ((c * 4 + n0) * 64 + lane) * 8;
    unsigned short* mh = fragMt + (size_t)t * 8192 + off;
    unsigned short* ch = fragC2 + (size_t)t * 8192 + off;
    for (int e = 0; e < 8; ++e) {
      float w = sM[(kb + e) * 64 + nn];
      unsigned short h = f2bf(w);
      mh[e] = h; mh[4096 + e] = f2bf(w - bf2f(h));
      float w2 = Wc2[t * 4096 + nn * 64 + (kb + e)];   // B_C2[j][p] = Wc2[p][j]
      unsigned short h2 = f2bf(w2);
      ch[e] = h2; ch[4096 + e] = f2bf(w2 - bf2f(h2));
    }
  }
  if (t == 0) {
    for (int idx = tid; idx < 1024; idx += 256) {
      int c = idx >> 8, n0 = (idx >> 6) & 3, lane = idx & 63;
      int kb = c * 32 + ((lane >> 4) << 3), nn = n0 * 16 + (lane & 15);
      int off = ((c * 4 + n0) * 64 + lane) * 8;
      for (int e = 0; e < 8; ++e) {
        float w = Wcomp[nn * 128 + kb + e];             // B_cmp[j][p] = Wcomp[p][j]
        unsigned short h = f2bf(w);
        fragCmp[off + e] = h; fragCmp[8192 + off + e] = f2bf(w - bf2f(h));
      }
    }
    for (int idx = tid; idx < 4096; idx += 256) {
      int j = idx >> 6, p = idx & 63;
      W7t[idx] = W7[p * 64 + j];
    }
  }
}

// ---------------- edge aggregation: feature-PAIR lanes, edge-parity halves ----------
__global__ __launch_bounds__(256) void k_agg(
    const int* __restrict__ beg_in, const int* __restrict__ end_in,
    const int* __restrict__ col_in,
    const int* __restrict__ beg_out, const int* __restrict__ end_out,
    const int* __restrict__ col_out,
    const unsigned short* __restrict__ mub, unsigned short* __restrict__ aggb_in,
    unsigned short* __restrict__ aggb_out, int n) {
  int wave = (blockIdx.x * blockDim.x + threadIdx.x) >> 6;
  int lane = threadIdx.x & 63;
  int half = lane >> 5;          // 0: even-index edges, 1: odd-index edges
  int fp = lane & 31;            // feature-pair index
  if (wave >= n) return;
  const unsigned int* __restrict__ mrow = (const unsigned int*)mub;
#pragma unroll
  for (int dir = 0; dir < 2; ++dir) {
    const int* __restrict__ bega = dir ? beg_out : beg_in;
    const int* __restrict__ enda = dir ? end_out : end_in;
    const int* __restrict__ col = dir ? col_out : col_in;
    unsigned short* __restrict__ aggb = dir ? aggb_out : aggb_in;
    int b = bega[wave], e = enda[wave];
    int cnt = e - b;
    int myn = (cnt > half) ? ((cnt - half + 1) >> 1) : 0;   // my half's edge count
    float ax[4], ay[4];
#pragma unroll
    for (int u = 0; u < 4; ++u) { ax[u] = 0.f; ay[u] = 0.f; }
    int base = b + half;
    int i = 0;
    int bulk = myn & ~7;
    for (; i < bulk; i += 8) {            // bulk: no masks
      int idx[8];
#pragma unroll
      for (int u = 0; u < 8; ++u) idx[u] = col[base + 2 * (i + u)];
      unsigned int v[8];
#pragma unroll
      for (int u = 0; u < 8; ++u) v[u] = mrow[((size_t)idx[u] << 5) + fp];
#pragma unroll
      for (int u = 0; u < 8; ++u) {
        ax[u & 3] += __uint_as_float(v[u] << 16);
        ay[u & 3] += __uint_as_float(v[u] & 0xFFFF0000u);
      }
    }
    if (i < myn) {                        // single masked tail group
      int last = myn - 1;
      int idx[8];
      float msk[8];
#pragma unroll
      for (int u = 0; u < 8; ++u) {
        int kk = i + u;
        idx[u] = col[base + 2 * (kk <= last ? kk : last)];
        msk[u] = (kk <= last) ? 1.f : 0.f;
      }
      unsigned int v[8];
#pragma unroll
      for (int u = 0; u < 8; ++u) v[u] = mrow[((size_t)idx[u] << 5) + fp];
#pragma unroll
      for (int u = 0; u < 8; ++u) {
        ax[u & 3] = fmaf(msk[u], __uint_as_float(v[u] << 16), ax[u & 3]);
        ay[u & 3] = fmaf(msk[u], __uint_as_float(v[u] & 0xFFFF0000u), ay[u & 3]);
      }
    }
    float sx = (ax[0] + ax[1]) + (ax[2] + ax[3]);
    float sy = (ay[0] + ay[1]) + (ay[2] + ay[3]);
    sx += __shfl_xor(sx, 32);             // merge even/odd halves
    sy += __shfl_xor(sy, 32);
    unsigned short h0 = f2bf(sx), h1 = f2bf(sy);
    unsigned short l0 = f2bf(sx - bf2f(h0)), l1 = f2bf(sy - bf2f(h1));
    unsigned int pack = half ? ((unsigned)l0 | ((unsigned)l1 << 16))
                             : ((unsigned)h0 | ((unsigned)h1 << 16));
    ((unsigned int*)aggb)[(size_t)wave * 64 + lane] = pack;   // coalesced 256B
  }
}

// ---------------- MFMA k_node helpers (M=2: wave owns 32 nodes) ----------------
__device__ __forceinline__ void load_alds(const unsigned int* qp, s8v& ah, s8v& al) {
  uint4 qa = *(const uint4*)qp;
  uint4 qb = *(const uint4*)(qp + 4);
  U8 uh, ul;
  uh.w[0] = (qa.x & 0xFFFFu) | (qa.y << 16);
  uh.w[1] = (qa.z & 0xFFFFu) | (qa.w << 16);
  uh.w[2] = (qb.x & 0xFFFFu) | (qb.y << 16);
  uh.w[3] = (qb.z & 0xFFFFu) | (qb.w << 16);
  ul.w[0] = (qa.x >> 16) | (qa.y & 0xFFFF0000u);
  ul.w[1] = (qa.z >> 16) | (qa.w & 0xFFFF0000u);
  ul.w[2] = (qb.x >> 16) | (qb.y & 0xFFFF0000u);
  ul.w[3] = (qb.z >> 16) | (qb.w & 0xFFFF0000u);
  ah = uh.v;
  al = ul.v;
}

// stage one 16KB weight fragment set (4096 hi + 4096 lo shorts) into LDS slot
__device__ __forceinline__ void stageW(unsigned int* sW, const unsigned short* hi,
                                       const unsigned short* lo, int tid) {
  __syncthreads();   // previous consumers done
  uint4* d = (uint4*)sW;
  const uint4* h = (const uint4*)hi;
  const uint4* l = (const uint4*)lo;
  for (int i = tid; i < 512; i += 256) d[i] = h[i];
  for (int i = tid; i < 512; i += 256) d[512 + i] = l[i];
  __syncthreads();   // staged data visible
}

// gemm with A from wave-private zhl tile, B from the staged LDS weight slot
__device__ __forceinline__ void gemm_lds(const unsigned int (*zhl)[76],
                                         const unsigned short* sW,
                                         int lane, f4v acc[2][4]) {
  int lrow = lane & 15, lgrp = lane >> 4;
#pragma unroll
  for (int kc = 0; kc < 2; ++kc) {
    s8v Ah[2], Al[2];
#pragma unroll
    for (int m = 0; m < 2; ++m)
      load_alds(&zhl[m * 16 + lrow][kc * 32 + lgrp * 8], Ah[m], Al[m]);
#pragma unroll
    for (int nn = 0; nn < 4; ++nn) {
      const unsigned short* bp = sW + ((kc * 4 + nn) * 64 + lane) * 8;
      s8v Bh = *(const s8v*)bp;
      s8v Bl = *(const s8v*)(bp + 4096);
#pragma unroll
      for (int m = 0; m < 2; ++m) {
        acc[m][nn] = MFMA(Ah[m], Bh, acc[m][nn]);
        acc[m][nn] = MFMA(Al[m], Bh, acc[m][nn]);
        acc[m][nn] = MFMA(Ah[m], Bl, acc[m][nn]);
      }
    }
  }
}

__device__ __forceinline__ void store_zhl(unsigned int (*zhl)[76], const f4v acc[2][4],
                                          int lane) {
  int lrow = lane & 15, lgrp = lane >> 4;
#pragma unroll
  for (int m = 0; m < 2; ++m)
#pragma unroll
    for (int nn = 0; nn < 4; ++nn)
#pragma unroll
      for (int r = 0; r < 4; ++r) {
        float v = fmaxf(acc[m][nn][r], 0.f);
        unsigned short h = f2bf(v);
        unsigned short l = f2bf(v - bf2f(h));
        zhl[m * 16 + lgrp * 4 + r][nn * 16 + lrow] = (unsigned)h | ((unsigned)l << 16);
      }
}

// ---------------- fused per-node GEMM chain on the MATRIX pipe ----------------
// Block = 4 waves x 32 nodes (M=2). Weights live in ONE rotating 16KB LDS slot,
// staged 6x per block (coalesced, between barriers) -> B reads are ds_read_b128,
// no global-load hoisting, no spills; weights fetched once per BLOCK not per wave.
// LDS = 16KB slot + 4x9.5KB zhl = 54KB -> 2 blocks/CU. No early returns (uniform
// barriers); loads clamped, stores guarded.
__global__ __launch_bounds__(256, 2) void k_node(
    const float* __restrict__ x, const float* __restrict__ sw_in,
    const float* __restrict__ sw_out, const unsigned short* __restrict__ aggb_in,
    const unsigned short* __restrict__ aggb_out, const float* __restrict__ c1g,
    const float* __restrict__ c3g, const unsigned short* __restrict__ fragMt,
    const unsigned short* __restrict__ fragC2, const unsigned short* __restrict__ fragCmp,
    float* __restrict__ mu, unsigned short* __restrict__ mub,
    int n, int t, int haveAgg, int last) {
  __shared__ unsigned int sW[4096];          // 16KB rotating weight slot
  __shared__ unsigned int zhlB[4][32][76];   // per-wave z tiles (38.9KB)
  int tid = threadIdx.x;
  int lane = tid & 63, w = tid >> 6;
  int lrow = lane & 15, lgrp = lane >> 4;
  int node0 = blockIdx.x * 128 + w * 32;
  unsigned int (*zhl)[76] = zhlB[w];
  const unsigned short* fMt = fragMt + (size_t)t * 8192;
  const unsigned short* fC2 = fragC2 + (size_t)t * 8192;
  float c1v[4], c3v[4];
#pragma unroll
  for (int nn = 0; nn < 4; ++nn) {
    c1v[nn] = c1g[t * 64 + nn * 16 + lrow];
    c3v[nn] = c3g[t * 64 + nn * 16 + lrow];
  }
  f4v accO[2][4];
#pragma unroll
  for (int m = 0; m < 2; ++m)
#pragma unroll
    for (int nn = 0; nn < 4; ++nn) accO[m][nn] = (f4v){0.f, 0.f, 0.f, 0.f};

#pragma unroll 1
  for (int dir = 0; dir < 2; ++dir) {
    const unsigned short* aggb = dir ? aggb_out : aggb_in;
    const float* sw = dir ? sw_out : sw_in;
    f4v acc[2][4];
#pragma unroll
    for (int m = 0; m < 2; ++m)
#pragma unroll
      for (int r = 0; r < 4; ++r) {
        int nd = node0 + m * 16 + lgrp * 4 + r;
        nd = nd < n ? nd : n - 1;
        float xl = x[nd], sl = sw[nd];
#pragma unroll
        for (int nn = 0; nn < 4; ++nn) acc[m][nn][r] = xl * c1v[nn] + sl * c3v[nn];
      }
    if (haveAgg) {   // z += agg @ Mt  (Mt staged in LDS; A rows from global, clamped)
      stageW(sW, fMt, fMt + 4096, tid);
#pragma unroll
      for (int kc = 0; kc < 2; ++kc) {
        s8v Ah[2], Al[2];
#pragma unroll
        for (int m = 0; m < 2; ++m) {
          int nd = node0 + m * 16 + lrow;
          nd = nd < n ? nd : n - 1;
          const unsigned short* ap = aggb + (size_t)nd * 128 + kc * 32 + lgrp * 8;
          Ah[m] = *(const s8v*)ap;
          Al[m] = *(const s8v*)(ap + 64);
        }
#pragma unroll
        for (int nn = 0; nn < 4; ++nn) {
          const unsigned short* bp =
              (const unsigned short*)sW + ((kc * 4 + nn) * 64 + lane) * 8;
          s8v Bh = *(const s8v*)bp;
          s8v Bl = *(const s8v*)(bp + 4096);
#pragma unroll
          for (int m = 0; m < 2; ++m) {
            acc[m][nn] = MFMA(Ah[m], Bh, acc[m][nn]);
            acc[m][nn] = MFMA(Al[m], Bh, acc[m][nn]);
            acc[m][nn] = MFMA(Ah[m], Bl, acc[m][nn]);
          }
        }
      }
    }
    store_zhl(zhl, acc, lane);                 // z = relu(...)
    stageW(sW, fC2, fC2 + 4096, tid);          // barrier also covers zhl visibility
#pragma unroll
    for (int m = 0; m < 2; ++m)
#pragma unroll
      for (int nn = 0; nn < 4; ++nn) acc[m][nn] = (f4v){0.f, 0.f, 0.f, 0.f};
    gemm_lds(zhl, (const unsigned short*)sW, lane, acc);   // m = relu(z @ C2)
    store_zhl(zhl, acc, lane);
    stageW(sW, fragCmp + dir * 4096, fragCmp + 8192 + dir * 4096, tid);
    gemm_lds(zhl, (const unsigned short*)sW, lane, accO);  // o += m @ Cmp[dir]
  }
  if (last) {
#pragma unroll
    for (int m = 0; m < 2; ++m)
#pragma unroll
      for (int r = 0; r < 4; ++r) {
        int nd = node0 + m * 16 + lgrp * 4 + r;
        if (nd < n) {
#pragma unroll
          for (int nn = 0; nn < 4; ++nn)
            mu[(size_t)nd * 64 + nn * 16 + lrow] = fmaxf(accO[m][nn][r], 0.f);
        }
      }
  } else {
#pragma unroll
    for (int m = 0; m < 2; ++m)
#pragma unroll
      for (int r = 0; r < 4; ++r) {
        int nd = node0 + m * 16 + lgrp * 4 + r;
        if (nd < n) {
#pragma unroll
          for (int nn = 0; nn < 4; ++nn)
            mub[(size_t)nd * 64 + nn * 16 + lrow] = f2bf(fmaxf(accO[m][nn][r], 0.f));
        }
      }
  }
}

// ---------------- pooling: wave per 64-node chunk, ILP-8 fast path ----------------
__global__ __launch_bounds__(256) void k_pool(
    const float* __restrict__ mu, const int* __restrict__ batch,
    float* __restrict__ pool, int n) {
  int gw = (blockIdx.x * blockDim.x + threadIdx.x) >> 6;
  int lane = threadIdx.x & 63;
  int start = gw * 64;
  if (start >= n) return;
  int end = min(start + 64, n);
  int b0 = batch[start];
  if (b0 == batch[end - 1] && end - start == 64) {
    float a[8];
#pragma unroll
    for (int u = 0; u < 8; ++u) a[u] = 0.f;
#pragma unroll
    for (int g = 0; g < 8; ++g) {
#pragma unroll
      for (int u = 0; u < 8; ++u)
        a[u] += mu[(size_t)(start + g * 8 + u) * 64 + lane];   // 8 independent chains
    }
    float s = ((a[0] + a[1]) + (a[2] + a[3])) + ((a[4] + a[5]) + (a[6] + a[7]));
    atomicAdd(&pool[b0 * 64 + lane], s);
  } else {
    int cur = b0;
    float acc = 0.f;
    for (int i = start; i < end; ++i) {
      int b = batch[i];
      if (b != cur) {
        atomicAdd(&pool[cur * 64 + lane], acc);
        acc = 0.f;
        cur = b;
      }
      acc += mu[(size_t)i * 64 + lane];
    }
    atomicAdd(&pool[cur * 64 + lane], acc);
  }
}

__global__ void k_poolw6(const float* __restrict__ pool, const float* __restrict__ W6,
                         float* __restrict__ out) {
  int idx = blockIdx.x * blockDim.x + threadIdx.x;  // < 4096
  int g = idx >> 6, p = idx & 63;
  float s = 0.f;
  for (int k = 0; k < 64; ++k) s += pool[g * 64 + k] * W6[p * 64 + k];
  out[idx] = s;
}

// ---------------- head ----------------
__global__ __launch_bounds__(256) void k_final(
    const float* __restrict__ mu, const int* __restrict__ batch,
    const float* __restrict__ poolw6, const float* __restrict__ W7t,
    const float* __restrict__ W5, float* __restrict__ out, int n) {
  __shared__ float S[4][64];
  int tid = threadIdx.x, lane = tid & 63, w = tid >> 6;
  int node = blockIdx.x * 4 + w;
  if (node >= n) return;
  float mv = mu[(size_t)node * 64 + lane];
  S[w][lane] = mv;
  __builtin_amdgcn_wave_barrier();
  int g = batch[node];
  float t1 = fmaxf(poolw6[g * 64 + lane], 0.f);
  float acc = 0.f;
#pragma unroll 8
  for (int j = 0; j < 64; ++j) acc = fmaf(S[w][j], W7t[j * 64 + lane], acc);
  float t2 = fmaxf(acc, 0.f);
  float val = W5[lane] * t1 + W5[64 + lane] * t2;
  for (int off = 32; off > 0; off >>= 1) val += __shfl_down(val, off);
  if (lane == 0) out[node] = fmaxf(val, 0.f);
}

extern "C" void kernel_launch(void* const* d_in, const int* in_sizes, int n_in,
                              void* d_out, int out_size, void* d_ws, size_t ws_size,
                              hipStream_t stream) {
  const float* x = (const float*)d_in[0];
  const float* weight = (const float*)d_in[1];
  const int* ei = (const int*)d_in[2];
  const int* batch = (const int*)d_in[3];
  const float* W1 = (const float*)d_in[4];
  const float* W2 = (const float*)d_in[5];
  const float* W3 = (const float*)d_in[6];
  const float* W4 = (const float*)d_in[7];
  const float* Wc1 = (const float*)d_in[8];
  const float* Wc2 = (const float*)d_in[9];
  const float* Wcomp = (const float*)d_in[10];
  const float* W5 = (const float*)d_in[11];
  const float* W6 = (const float*)d_in[12];
  const float* W7 = (const float*)d_in[13];
  float* out = (float*)d_out;
  int N = in_sizes[0];
  int E = in_sizes[1];
  int T = in_sizes[4] / 64;

  int K = (N + RB - 1) / RB;
  int cap = E / K + E / (4 * K) + 1024;
  int Nw = ((N + 63) / 64) * 64;

  char* ws = (char*)d_ws;
  size_t off = 0;
  auto alloc = [&](size_t bytes) {
    size_t o = off;
    off += (bytes + 255) & ~(size_t)255;
    return o;
  };
  // zeroed region
  size_t o_bcnt = alloc((size_t)2 * K * 4);
  size_t o_pool = alloc(4096 * 4);
  size_t zero_end = off;
  size_t o_beg_in = alloc((size_t)N * 4);
  size_t o_end_in = alloc((size_t)N * 4);
  size_t o_beg_out = alloc((size_t)N * 4);
  size_t o_end_out = alloc((size_t)N * 4);
  size_t o_sw_in = alloc((size_t)N * 4);
  size_t o_sw_out = alloc((size_t)N * 4);
  size_t o_col_in = alloc((size_t)K * cap * 4);
  size_t o_col_out = alloc((size_t)K * cap * 4);
  size_t o_mu = alloc((size_t)Nw * 64 * 4);
  size_t o_mub = alloc((size_t)Nw * 64 * 2);   // bf16-hi mu for the gather
  size_t aggBytes = (size_t)Nw * 128 * 2;      // bf16 hi+lo planes
  size_t bktBytes = (size_t)K * cap * 8;
  size_t big = aggBytes > bktBytes ? aggBytes : bktBytes;
  size_t o_aggb_in = alloc(big);   // aliased: bkt_in during build
  size_t o_aggb_out = alloc(big);  // aliased: bkt_out during build
  size_t o_c1 = alloc(4 * 64 * 4);
  size_t o_c3 = alloc(4 * 64 * 4);
  size_t o_fragMt = alloc((size_t)4 * 8192 * 2);
  size_t o_fragC2 = alloc((size_t)4 * 8192 * 2);
  size_t o_fragCmp = alloc((size_t)16384 * 2);
  size_t o_W7t = alloc(4096 * 4);
  size_t o_poolw6 = alloc(4096 * 4);
  (void)ws_size; (void)n_in; (void)out_size;

  hipMemsetAsync(ws, 0, zero_end, stream);

  dim3 gBin((E + BIN_C - 1) / BIN_C, 2);
  k_bin<<<gBin, 256, 0, stream>>>(ei, weight, (uint2*)(ws + o_aggb_in),
                                  (uint2*)(ws + o_aggb_out), (int*)(ws + o_bcnt),
                                  E, K, cap);
  dim3 gBkt(K, 2);
  k_bucket<<<gBkt, 256, 0, stream>>>((uint2*)(ws + o_aggb_in), (uint2*)(ws + o_aggb_out),
                                     (int*)(ws + o_bcnt),
                                     (int*)(ws + o_beg_in), (int*)(ws + o_end_in),
                                     (int*)(ws + o_beg_out), (int*)(ws + o_end_out),
                                     (float*)(ws + o_sw_in), (float*)(ws + o_sw_out),
                                     (int*)(ws + o_col_in), (int*)(ws + o_col_out),
                                     cap, N, K);
  k_wprep<<<T, 256, 0, stream>>>(W1, W2, W3, W4, Wc1, Wc2, Wcomp, W7,
                                 (float*)(ws + o_c1), (float*)(ws + o_c3),
                                 (unsigned short*)(ws + o_fragMt),
                                 (unsigned short*)(ws + o_fragC2),
                                 (unsigned short*)(ws + o_fragCmp),
                                 (float*)(ws + o_W7t));

  int gN4 = (N + 3) / 4;
  int gNode = (Nw + 127) / 128;
  for (int t = 0; t < T; ++t) {
    if (t > 0)
      k_agg<<<gN4, 256, 0, stream>>>((int*)(ws + o_beg_in), (int*)(ws + o_end_in),
                                     (int*)(ws + o_col_in),
                                     (int*)(ws + o_beg_out), (int*)(ws + o_end_out),
                                     (int*)(ws + o_col_out),
                                     (unsigned short*)(ws + o_mub),
                                     (unsigned short*)(ws + o_aggb_in),
                                     (unsigned short*)(ws + o_aggb_out), N);
    k_node<<<gNode, 256, 0, stream>>>(x, (float*)(ws + o_sw_in), (float*)(ws + o_sw_out),
                                      (unsigned short*)(ws + o_aggb_in),
                                      (unsigned short*)(ws + o_aggb_out),
                                      (float*)(ws + o_c1), (float*)(ws + o_c3),
                                      (unsigned short*)(ws + o_fragMt),
                                      (unsigned short*)(ws + o_fragC2),
                                      (unsigned short*)(ws + o_fragCmp),
                                      (float*)(ws + o_mu),
                                      (unsigned short*)(ws + o_mub),
                                      N, t, t > 0 ? 1 : 0, t == T - 1 ? 1 : 0);
  }
  int gPool = ((N + 63) / 64 + 3) / 4;
  k_pool<<<gPool, 256, 0, stream>>>((float*)(ws + o_mu), batch, (float*)(ws + o_pool), N);
  k_poolw6<<<16, 256, 0, stream>>>((float*)(ws + o_pool), W6, (float*)(ws + o_poolw6));
  k_final<<<gN4, 256, 0, stream>>>((float*)(ws + o_mu), batch, (float*)(ws + o_poolw6),
                                   (float*)(ws + o_W7t), W5, out, N);
}

// Round 15
// 558.720 us; speedup vs baseline: 1.3340x; 1.0514x over previous
//
#include <hip/hip_runtime.h>

#define PD 64
#define BIN_C 6144   // edges per block in k_bin
#define RB 512       // nodes per bucket (log2 = 9)

typedef __attribute__((ext_vector_type(8))) short s8v;   // 8 bf16 (4 VGPRs)
typedef __attribute__((ext_vector_type(4))) float f4v;   // MFMA accumulator
#define MFMA(a, b, c) __builtin_amdgcn_mfma_f32_16x16x32_bf16(a, b, c, 0, 0, 0)

__device__ __forceinline__ unsigned short f2bf(float f) {   // RNE float->bf16
  unsigned u = __float_as_uint(f);
  return (unsigned short)((u + 0x7FFFu + ((u >> 16) & 1u)) >> 16);
}
__device__ __forceinline__ float bf2f(unsigned short h) {
  return __uint_as_float(((unsigned)h) << 16);
}
union U8 { unsigned int w[4]; s8v v; };

// ---------------- phase 1: bin edges by bucket (direct reserved writes) -------------
// Two passes over the tile: (1) LDS histogram; (2) reserve one global range per
// (block,bucket), then DIRECT per-edge writes at gbase[b]+rank. Each block-bucket
// range is ~250B so writes share lines; no staged reorder, no scan, no bin-search.
__global__ __launch_bounds__(256) void k_bin(const int* __restrict__ ei,
    const float* __restrict__ w, uint2* __restrict__ bkt_in, uint2* __restrict__ bkt_out,
    int* __restrict__ bcnt, int E, int K, int cap) {
  __shared__ int cnt[256], gbase[256], off[256];
  int dir = blockIdx.y;
  const int* __restrict__ keys = dir ? ei : ei + E;
  const int* __restrict__ vals = dir ? ei + E : ei;
  uint2* __restrict__ bdst = dir ? bkt_out : bkt_in;
  int tid = threadIdx.x;
  int e0 = blockIdx.x * BIN_C;
  int count = min(BIN_C, E - e0);
  cnt[tid] = 0;
  off[tid] = 0;
  __syncthreads();
  for (int i = tid; i < count; i += 256)
    atomicAdd(&cnt[keys[e0 + i] >> 9], 1);
  __syncthreads();
  if (tid < K) {
    int c = cnt[tid];
    gbase[tid] = c > 0 ? atomicAdd(&bcnt[dir * K + tid], c) : 0;
  }
  __syncthreads();
  for (int i = tid; i < count; i += 256) {
    int e = e0 + i;
    int k = keys[e];
    int b = k >> 9;
    unsigned int packed = ((unsigned int)vals[e] << 9) | (unsigned int)(k & (RB - 1));
    int rel = gbase[b] + atomicAdd(&off[b], 1);
    if (rel < cap) bdst[(size_t)b * cap + rel] = make_uint2(packed, __float_as_uint(w[e]));
  }
}

// ---------------- phase 2: per-bucket local CSR ----------------
__global__ __launch_bounds__(256) void k_bucket(
    const uint2* __restrict__ bkt_in, const uint2* __restrict__ bkt_out,
    const int* __restrict__ bcnt,
    int* __restrict__ beg_in, int* __restrict__ end_in,
    int* __restrict__ beg_out, int* __restrict__ end_out,
    float* __restrict__ sw_in, float* __restrict__ sw_out,
    int* __restrict__ col_in, int* __restrict__ col_out,
    int cap, int N, int K) {
  __shared__ int deg[RB], pos[RB], off[RB];
  __shared__ float swl[RB];
  __shared__ int ps[256];
  int b = blockIdx.x, dir = blockIdx.y, tid = threadIdx.x;
  const uint2* __restrict__ bkt = (dir ? bkt_out : bkt_in) + (size_t)b * cap;
  int* __restrict__ beg = dir ? beg_out : beg_in;
  int* __restrict__ end = dir ? end_out : end_in;
  float* __restrict__ swg = dir ? sw_out : sw_in;
  int* __restrict__ col = dir ? col_out : col_in;
  int len = bcnt[dir * K + b];
  if (len > cap) len = cap;
  deg[tid] = 0; deg[tid + 256] = 0;
  swl[tid] = 0.f; swl[tid + 256] = 0.f;
  __syncthreads();
  for (int i = tid; i < len; i += 256) {
    uint2 u = bkt[i];
    int l = u.x & (RB - 1);
    atomicAdd(&deg[l], 1);
    atomicAdd(&swl[l], __uint_as_float(u.y));
  }
  __syncthreads();
  int a0 = deg[2 * tid], a1 = deg[2 * tid + 1];
  ps[tid] = a0 + a1;
  __syncthreads();
  for (int o = 1; o < 256; o <<= 1) {
    int t = (tid >= o) ? ps[tid - o] : 0;
    __syncthreads();
    ps[tid] += t;
    __syncthreads();
  }
  int ex = ps[tid] - (a0 + a1);
  pos[2 * tid] = ex;
  pos[2 * tid + 1] = ex + a0;
  off[tid] = 0; off[tid + 256] = 0;
  __syncthreads();
  int base_node = b << 9;
  size_t colbase = (size_t)b * cap;
  for (int l = tid; l < RB; l += 256) {
    int g = base_node + l;
    if (g < N) {
      beg[g] = (int)(colbase + pos[l]);
      end[g] = (int)(colbase + pos[l] + deg[l]);
      swg[g] = swl[l];
    }
  }
  __syncthreads();
  for (int i = tid; i < len; i += 256) {
    uint2 u = bkt[i];
    int l = u.x & (RB - 1);
    int s = (int)(u.x >> 9);
    int p = pos[l] + atomicAdd(&off[l], 1);
    col[colbase + p] = s;
  }
}

// ---------------- weight folding + MFMA fragment packing ----------------
__global__ void k_wprep(const float* __restrict__ W1, const float* __restrict__ W2,
                        const float* __restrict__ W3, const float* __restrict__ W4,
                        const float* __restrict__ Wc1, const float* __restrict__ Wc2,
                        const float* __restrict__ Wcomp, const float* __restrict__ W7,
                        float* c1, float* c3, unsigned short* fragMt,
                        unsigned short* fragC2, unsigned short* fragCmp, float* W7t) {
  int t = blockIdx.x;
  int tid = threadIdx.x;
  __shared__ float r4[64], v3[64];
  __shared__ float sM[4096];
  if (tid < 64) r4[tid] = fmaxf(W4[t * 64 + tid], 0.f);
  __syncthreads();
  if (tid < 64) {
    float s = 0.f;
    for (int k = 0; k < 64; ++k) s += W3[t * 4096 + tid * 64 + k] * r4[k];
    v3[tid] = s;
    float s1 = 0.f;
    for (int k = 0; k < 64; ++k) s1 += Wc1[t * 12288 + tid * 192 + k] * W1[t * 64 + k];
    c1[t * 64 + tid] = s1;
  }
  __syncthreads();
  if (tid < 64) {
    float s = 0.f;
    for (int k = 0; k < 64; ++k) s += Wc1[t * 12288 + tid * 192 + 128 + k] * v3[k];
    c3[t * 64 + tid] = s;
  }
  for (int idx = tid; idx < 4096; idx += 256) {
    int j = idx >> 6, p = idx & 63;
    float s = 0.f;
    for (int k = 0; k < 64; ++k)
      s += Wc1[t * 12288 + p * 192 + 64 + k] * W2[t * 4096 + k * 64 + j];
    sM[j * 64 + p] = s;   // B_Mt[j][p]
  }
  __syncthreads();
  for (int idx = tid; idx < 512; idx += 256) {
    int c = idx >> 8, n0 = (idx >> 6) & 3, lane = idx & 63;
    int kb = c * 32 + ((lane >> 4) << 3), nn = n0 * 16 + (lane & 15);
    int off = ((c * 4 + n0) * 64 + lane) * 8;
    unsigned short* mh = fragMt + (size_t)t * 8192 + off;
    unsigned short* ch = fragC2 + (size_t)t * 8192 + off;
    for (int e = 0; e < 8; ++e) {
      float w = sM[(kb + e) * 64 + nn];
      unsigned short h = f2bf(w);
      mh[e] = h; mh[4096 + e] = f2bf(w - bf2f(h));
      float w2 = Wc2[t * 4096 + nn * 64 + (kb + e)];   // B_C2[j][p] = Wc2[p][j]
      unsigned short h2 = f2bf(w2);
      ch[e] = h2; ch[4096 + e] = f2bf(w2 - bf2f(h2));
    }
  }
  if (t == 0) {
    for (int idx = tid; idx < 1024; idx += 256) {
      int c = idx >> 8, n0 = (idx >> 6) & 3, lane = idx & 63;
      int kb = c * 32 + ((lane >> 4) << 3), nn = n0 * 16 + (lane & 15);
      int off = ((c * 4 + n0) * 64 + lane) * 8;
      for (int e = 0; e < 8; ++e) {
        float w = Wcomp[nn * 128 + kb + e];             // B_cmp[j][p] = Wcomp[p][j]
        unsigned short h = f2bf(w);
        fragCmp[off + e] = h; fragCmp[8192 + off + e] = f2bf(w - bf2f(h));
      }
    }
    for (int idx = tid; idx < 4096; idx += 256) {
      int j = idx >> 6, p = idx & 63;
      W7t[idx] = W7[p * 64 + j];
    }
  }
}

// ---------------- edge aggregation: feature-PAIR lanes, edge-parity halves ----------
__global__ __launch_bounds__(256) void k_agg(
    const int* __restrict__ beg_in, const int* __restrict__ end_in,
    const int* __restrict__ col_in,
    const int* __restrict__ beg_out, const int* __restrict__ end_out,
    const int* __restrict__ col_out,
    const unsigned short* __restrict__ mub, unsigned short* __restrict__ aggb_in,
    unsigned short* __restrict__ aggb_out, int n) {
  int wave = (blockIdx.x * blockDim.x + threadIdx.x) >> 6;
  int lane = threadIdx.x & 63;
  int half = lane >> 5;          // 0: even-index edges, 1: odd-index edges
  int fp = lane & 31;            // feature-pair index
  if (wave >= n) return;
  const unsigned int* __restrict__ mrow = (const unsigned int*)mub;
#pragma unroll
  for (int dir = 0; dir < 2; ++dir) {
    const int* __restrict__ bega = dir ? beg_out : beg_in;
    const int* __restrict__ enda = dir ? end_out : end_in;
    const int* __restrict__ col = dir ? col_out : col_in;
    unsigned short* __restrict__ aggb = dir ? aggb_out : aggb_in;
    int b = bega[wave], e = enda[wave];
    int cnt = e - b;
    int myn = (cnt > half) ? ((cnt - half + 1) >> 1) : 0;   // my half's edge count
    float ax[4], ay[4];
#pragma unroll
    for (int u = 0; u < 4; ++u) { ax[u] = 0.f; ay[u] = 0.f; }
    int base = b + half;
    int i = 0;
    int bulk = myn & ~7;
    for (; i < bulk; i += 8) {            // bulk: no masks
      int idx[8];
#pragma unroll
      for (int u = 0; u < 8; ++u) idx[u] = col[base + 2 * (i + u)];
      unsigned int v[8];
#pragma unroll
      for (int u = 0; u < 8; ++u) v[u] = mrow[((size_t)idx[u] << 5) + fp];
#pragma unroll
      for (int u = 0; u < 8; ++u) {
        ax[u & 3] += __uint_as_float(v[u] << 16);
        ay[u & 3] += __uint_as_float(v[u] & 0xFFFF0000u);
      }
    }
    if (i < myn) {                        // single masked tail group
      int last = myn - 1;
      int idx[8];
      float msk[8];
#pragma unroll
      for (int u = 0; u < 8; ++u) {
        int kk = i + u;
        idx[u] = col[base + 2 * (kk <= last ? kk : last)];
        msk[u] = (kk <= last) ? 1.f : 0.f;
      }
      unsigned int v[8];
#pragma unroll
      for (int u = 0; u < 8; ++u) v[u] = mrow[((size_t)idx[u] << 5) + fp];
#pragma unroll
      for (int u = 0; u < 8; ++u) {
        ax[u & 3] = fmaf(msk[u], __uint_as_float(v[u] << 16), ax[u & 3]);
        ay[u & 3] = fmaf(msk[u], __uint_as_float(v[u] & 0xFFFF0000u), ay[u & 3]);
      }
    }
    float sx = (ax[0] + ax[1]) + (ax[2] + ax[3]);
    float sy = (ay[0] + ay[1]) + (ay[2] + ay[3]);
    sx += __shfl_xor(sx, 32);             // merge even/odd halves
    sy += __shfl_xor(sy, 32);
    unsigned short h0 = f2bf(sx), h1 = f2bf(sy);
    unsigned short l0 = f2bf(sx - bf2f(h0)), l1 = f2bf(sy - bf2f(h1));
    unsigned int pack = half ? ((unsigned)l0 | ((unsigned)l1 << 16))
                             : ((unsigned)h0 | ((unsigned)h1 << 16));
    ((unsigned int*)aggb)[(size_t)wave * 64 + lane] = pack;   // coalesced 256B
  }
}

// ---------------- MFMA k_node helpers (M=2: wave owns 32 nodes) ----------------
__device__ __forceinline__ void load_alds(const unsigned int* qp, s8v& ah, s8v& al) {
  uint4 qa = *(const uint4*)qp;
  uint4 qb = *(const uint4*)(qp + 4);
  U8 uh, ul;
  uh.w[0] = (qa.x & 0xFFFFu) | (qa.y << 16);
  uh.w[1] = (qa.z & 0xFFFFu) | (qa.w << 16);
  uh.w[2] = (qb.x & 0xFFFFu) | (qb.y << 16);
  uh.w[3] = (qb.z & 0xFFFFu) | (qb.w << 16);
  ul.w[0] = (qa.x >> 16) | (qa.y & 0xFFFF0000u);
  ul.w[1] = (qa.z >> 16) | (qa.w & 0xFFFF0000u);
  ul.w[2] = (qb.x >> 16) | (qb.y & 0xFFFF0000u);
  ul.w[3] = (qb.z >> 16) | (qb.w & 0xFFFF0000u);
  ah = uh.v;
  al = ul.v;
}

// stage one 16KB weight fragment set (4096 hi + 4096 lo shorts) into LDS slot
__device__ __forceinline__ void stageW(unsigned int* sW, const unsigned short* hi,
                                       const unsigned short* lo, int tid) {
  __syncthreads();   // previous consumers done
  uint4* d = (uint4*)sW;
  const uint4* h = (const uint4*)hi;
  const uint4* l = (const uint4*)lo;
  for (int i = tid; i < 512; i += 256) d[i] = h[i];
  for (int i = tid; i < 512; i += 256) d[512 + i] = l[i];
  __syncthreads();   // staged data visible
}

// gemm with A from wave-private zhl tile, B from the staged LDS weight slot
__device__ __forceinline__ void gemm_lds(const unsigned int (*zhl)[76],
                                         const unsigned short* sW,
                                         int lane, f4v acc[2][4]) {
  int lrow = lane & 15, lgrp = lane >> 4;
#pragma unroll
  for (int kc = 0; kc < 2; ++kc) {
    s8v Ah[2], Al[2];
#pragma unroll
    for (int m = 0; m < 2; ++m)
      load_alds(&zhl[m * 16 + lrow][kc * 32 + lgrp * 8], Ah[m], Al[m]);
#pragma unroll
    for (int nn = 0; nn < 4; ++nn) {
      const unsigned short* bp = sW + ((kc * 4 + nn) * 64 + lane) * 8;
      s8v Bh = *(const s8v*)bp;
      s8v Bl = *(const s8v*)(bp + 4096);
#pragma unroll
      for (int m = 0; m < 2; ++m) {
        acc[m][nn] = MFMA(Ah[m], Bh, acc[m][nn]);
        acc[m][nn] = MFMA(Al[m], Bh, acc[m][nn]);
        acc[m][nn] = MFMA(Ah[m], Bl, acc[m][nn]);
      }
    }
  }
}

__device__ __forceinline__ void store_zhl(unsigned int (*zhl)[76], const f4v acc[2][4],
                                          int lane) {
  int lrow = lane & 15, lgrp = lane >> 4;
#pragma unroll
  for (int m = 0; m < 2; ++m)
#pragma unroll
    for (int nn = 0; nn < 4; ++nn)
#pragma unroll
      for (int r = 0; r < 4; ++r) {
        float v = fmaxf(acc[m][nn][r], 0.f);
        unsigned short h = f2bf(v);
        unsigned short l = f2bf(v - bf2f(h));
        zhl[m * 16 + lgrp * 4 + r][nn * 16 + lrow] = (unsigned)h | ((unsigned)l << 16);
      }
}

// ---------------- fused per-node GEMM chain on the MATRIX pipe ----------------
// Block = 4 waves x 32 nodes (M=2). Weights live in ONE rotating 16KB LDS slot,
// staged 6x per block (coalesced, between barriers) -> B reads are ds_read_b128,
// no global-load hoisting, no spills; weights fetched once per BLOCK not per wave.
__global__ __launch_bounds__(256, 2) void k_node(
    const float* __restrict__ x, const float* __restrict__ sw_in,
    const float* __restrict__ sw_out, const unsigned short* __restrict__ aggb_in,
    const unsigned short* __restrict__ aggb_out, const float* __restrict__ c1g,
    const float* __restrict__ c3g, const unsigned short* __restrict__ fragMt,
    const unsigned short* __restrict__ fragC2, const unsigned short* __restrict__ fragCmp,
    float* __restrict__ mu, unsigned short* __restrict__ mub,
    int n, int t, int haveAgg, int last) {
  __shared__ unsigned int sW[4096];          // 16KB rotating weight slot
  __shared__ unsigned int zhlB[4][32][76];   // per-wave z tiles (38.9KB)
  int tid = threadIdx.x;
  int lane = tid & 63, w = tid >> 6;
  int lrow = lane & 15, lgrp = lane >> 4;
  int node0 = blockIdx.x * 128 + w * 32;
  unsigned int (*zhl)[76] = zhlB[w];
  const unsigned short* fMt = fragMt + (size_t)t * 8192;
  const unsigned short* fC2 = fragC2 + (size_t)t * 8192;
  float c1v[4], c3v[4];
#pragma unroll
  for (int nn = 0; nn < 4; ++nn) {
    c1v[nn] = c1g[t * 64 + nn * 16 + lrow];
    c3v[nn] = c3g[t * 64 + nn * 16 + lrow];
  }
  f4v accO[2][4];
#pragma unroll
  for (int m = 0; m < 2; ++m)
#pragma unroll
    for (int nn = 0; nn < 4; ++nn) accO[m][nn] = (f4v){0.f, 0.f, 0.f, 0.f};

#pragma unroll 1
  for (int dir = 0; dir < 2; ++dir) {
    const unsigned short* aggb = dir ? aggb_out : aggb_in;
    const float* sw = dir ? sw_out : sw_in;
    f4v acc[2][4];
#pragma unroll
    for (int m = 0; m < 2; ++m)
#pragma unroll
      for (int r = 0; r < 4; ++r) {
        int nd = node0 + m * 16 + lgrp * 4 + r;
        nd = nd < n ? nd : n - 1;
        float xl = x[nd], sl = sw[nd];
#pragma unroll
        for (int nn = 0; nn < 4; ++nn) acc[m][nn][r] = xl * c1v[nn] + sl * c3v[nn];
      }
    if (haveAgg) {   // z += agg @ Mt  (Mt staged in LDS; A rows from global, clamped)
      stageW(sW, fMt, fMt + 4096, tid);
#pragma unroll
      for (int kc = 0; kc < 2; ++kc) {
        s8v Ah[2], Al[2];
#pragma unroll
        for (int m = 0; m < 2; ++m) {
          int nd = node0 + m * 16 + lrow;
          nd = nd < n ? nd : n - 1;
          const unsigned short* ap = aggb + (size_t)nd * 128 + kc * 32 + lgrp * 8;
          Ah[m] = *(const s8v*)ap;
          Al[m] = *(const s8v*)(ap + 64);
        }
#pragma unroll
        for (int nn = 0; nn < 4; ++nn) {
          const unsigned short* bp =
              (const unsigned short*)sW + ((kc * 4 + nn) * 64 + lane) * 8;
          s8v Bh = *(const s8v*)bp;
          s8v Bl = *(const s8v*)(bp + 4096);
#pragma unroll
          for (int m = 0; m < 2; ++m) {
            acc[m][nn] = MFMA(Ah[m], Bh, acc[m][nn]);
            acc[m][nn] = MFMA(Al[m], Bh, acc[m][nn]);
            acc[m][nn] = MFMA(Ah[m], Bl, acc[m][nn]);
          }
        }
      }
    }
    store_zhl(zhl, acc, lane);                 // z = relu(...)
    stageW(sW, fC2, fC2 + 4096, tid);          // barrier also covers zhl visibility
#pragma unroll
    for (int m = 0; m < 2; ++m)
#pragma unroll
      for (int nn = 0; nn < 4; ++nn) acc[m][nn] = (f4v){0.f, 0.f, 0.f, 0.f};
    gemm_lds(zhl, (const unsigned short*)sW, lane, acc);   // m = relu(z @ C2)
    store_zhl(zhl, acc, lane);
    stageW(sW, fragCmp + dir * 4096, fragCmp + 8192 + dir * 4096, tid);
    gemm_lds(zhl, (const unsigned short*)sW, lane, accO);  // o += m @ Cmp[dir]
  }
  if (last) {
#pragma unroll
    for (int m = 0; m < 2; ++m)
#pragma unroll
      for (int r = 0; r < 4; ++r) {
        int nd = node0 + m * 16 + lgrp * 4 + r;
        if (nd < n) {
#pragma unroll
          for (int nn = 0; nn < 4; ++nn)
            mu[(size_t)nd * 64 + nn * 16 + lrow] = fmaxf(accO[m][nn][r], 0.f);
        }
      }
  } else {
#pragma unroll
    for (int m = 0; m < 2; ++m)
#pragma unroll
      for (int r = 0; r < 4; ++r) {
        int nd = node0 + m * 16 + lgrp * 4 + r;
        if (nd < n) {
#pragma unroll
          for (int nn = 0; nn < 4; ++nn)
            mub[(size_t)nd * 64 + nn * 16 + lrow] = f2bf(fmaxf(accO[m][nn][r], 0.f));
        }
      }
  }
}

// ---------------- pooling: wave per 64-node chunk, ILP-8 fast path ----------------
__global__ __launch_bounds__(256) void k_pool(
    const float* __restrict__ mu, const int* __restrict__ batch,
    float* __restrict__ pool, int n) {
  int gw = (blockIdx.x * blockDim.x + threadIdx.x) >> 6;
  int lane = threadIdx.x & 63;
  int start = gw * 64;
  if (start >= n) return;
  int end = min(start + 64, n);
  int b0 = batch[start];
  if (b0 == batch[end - 1] && end - start == 64) {
    float a[8];
#pragma unroll
    for (int u = 0; u < 8; ++u) a[u] = 0.f;
#pragma unroll
    for (int g = 0; g < 8; ++g) {
#pragma unroll
      for (int u = 0; u < 8; ++u)
        a[u] += mu[(size_t)(start + g * 8 + u) * 64 + lane];   // 8 independent chains
    }
    float s = ((a[0] + a[1]) + (a[2] + a[3])) + ((a[4] + a[5]) + (a[6] + a[7]));
    atomicAdd(&pool[b0 * 64 + lane], s);
  } else {
    int cur = b0;
    float acc = 0.f;
    for (int i = start; i < end; ++i) {
      int b = batch[i];
      if (b != cur) {
        atomicAdd(&pool[cur * 64 + lane], acc);
        acc = 0.f;
        cur = b;
      }
      acc += mu[(size_t)i * 64 + lane];
    }
    atomicAdd(&pool[cur * 64 + lane], acc);
  }
}

__global__ void k_poolw6(const float* __restrict__ pool, const float* __restrict__ W6,
                         float* __restrict__ out) {
  int idx = blockIdx.x * blockDim.x + threadIdx.x;  // < 4096
  int g = idx >> 6, p = idx & 63;
  float s = 0.f;
  for (int k = 0; k < 64; ++k) s += pool[g * 64 + k] * W6[p * 64 + k];
  out[idx] = s;
}

// ---------------- head ----------------
__global__ __launch_bounds__(256) void k_final(
    const float* __restrict__ mu, const int* __restrict__ batch,
    const float* __restrict__ poolw6, const float* __restrict__ W7t,
    const float* __restrict__ W5, float* __restrict__ out, int n) {
  __shared__ float S[4][64];
  int tid = threadIdx.x, lane = tid & 63, w = tid >> 6;
  int node = blockIdx.x * 4 + w;
  if (node >= n) return;
  float mv = mu[(size_t)node * 64 + lane];
  S[w][lane] = mv;
  __builtin_amdgcn_wave_barrier();
  int g = batch[node];
  float t1 = fmaxf(poolw6[g * 64 + lane], 0.f);
  float acc = 0.f;
#pragma unroll 8
  for (int j = 0; j < 64; ++j) acc = fmaf(S[w][j], W7t[j * 64 + lane], acc);
  float t2 = fmaxf(acc, 0.f);
  float val = W5[lane] * t1 + W5[64 + lane] * t2;
  for (int off = 32; off > 0; off >>= 1) val += __shfl_down(val, off);
  if (lane == 0) out[node] = fmaxf(val, 0.f);
}

extern "C" void kernel_launch(void* const* d_in, const int* in_sizes, int n_in,
                              void* d_out, int out_size, void* d_ws, size_t ws_size,
                              hipStream_t stream) {
  const float* x = (const float*)d_in[0];
  const float* weight = (const float*)d_in[1];
  const int* ei = (const int*)d_in[2];
  const int* batch = (const int*)d_in[3];
  const float* W1 = (const float*)d_in[4];
  const float* W2 = (const float*)d_in[5];
  const float* W3 = (const float*)d_in[6];
  const float* W4 = (const float*)d_in[7];
  const float* Wc1 = (const float*)d_in[8];
  const float* Wc2 = (const float*)d_in[9];
  const float* Wcomp = (const float*)d_in[10];
  const float* W5 = (const float*)d_in[11];
  const float* W6 = (const float*)d_in[12];
  const float* W7 = (const float*)d_in[13];
  float* out = (float*)d_out;
  int N = in_sizes[0];
  int E = in_sizes[1];
  int T = in_sizes[4] / 64;

  int K = (N + RB - 1) / RB;
  int cap = E / K + E / (4 * K) + 1024;
  int Nw = ((N + 63) / 64) * 64;

  char* ws = (char*)d_ws;
  size_t off = 0;
  auto alloc = [&](size_t bytes) {
    size_t o = off;
    off += (bytes + 255) & ~(size_t)255;
    return o;
  };
  // zeroed region
  size_t o_bcnt = alloc((size_t)2 * K * 4);
  size_t o_pool = alloc(4096 * 4);
  size_t zero_end = off;
  size_t o_beg_in = alloc((size_t)N * 4);
  size_t o_end_in = alloc((size_t)N * 4);
  size_t o_beg_out = alloc((size_t)N * 4);
  size_t o_end_out = alloc((size_t)N * 4);
  size_t o_sw_in = alloc((size_t)N * 4);
  size_t o_sw_out = alloc((size_t)N * 4);
  size_t o_col_in = alloc((size_t)K * cap * 4);
  size_t o_col_out = alloc((size_t)K * cap * 4);
  size_t o_mu = alloc((size_t)Nw * 64 * 4);
  size_t o_mub = alloc((size_t)Nw * 64 * 2);   // bf16-hi mu for the gather
  size_t aggBytes = (size_t)Nw * 128 * 2;      // bf16 hi+lo planes
  size_t bktBytes = (size_t)K * cap * 8;
  size_t big = aggBytes > bktBytes ? aggBytes : bktBytes;
  size_t o_aggb_in = alloc(big);   // aliased: bkt_in during build
  size_t o_aggb_out = alloc(big);  // aliased: bkt_out during build
  size_t o_c1 = alloc(4 * 64 * 4);
  size_t o_c3 = alloc(4 * 64 * 4);
  size_t o_fragMt = alloc((size_t)4 * 8192 * 2);
  size_t o_fragC2 = alloc((size_t)4 * 8192 * 2);
  size_t o_fragCmp = alloc((size_t)16384 * 2);
  size_t o_W7t = alloc(4096 * 4);
  size_t o_poolw6 = alloc(4096 * 4);
  (void)ws_size; (void)n_in; (void)out_size;

  hipMemsetAsync(ws, 0, zero_end, stream);

  dim3 gBin((E + BIN_C - 1) / BIN_C, 2);
  k_bin<<<gBin, 256, 0, stream>>>(ei, weight, (uint2*)(ws + o_aggb_in),
                                  (uint2*)(ws + o_aggb_out), (int*)(ws + o_bcnt),
                                  E, K, cap);
  dim3 gBkt(K, 2);
  k_bucket<<<gBkt, 256, 0, stream>>>((uint2*)(ws + o_aggb_in), (uint2*)(ws + o_aggb_out),
                                     (int*)(ws + o_bcnt),
                                     (int*)(ws + o_beg_in), (int*)(ws + o_end_in),
                                     (int*)(ws + o_beg_out), (int*)(ws + o_end_out),
                                     (float*)(ws + o_sw_in), (float*)(ws + o_sw_out),
                                     (int*)(ws + o_col_in), (int*)(ws + o_col_out),
                                     cap, N, K);
  k_wprep<<<T, 256, 0, stream>>>(W1, W2, W3, W4, Wc1, Wc2, Wcomp, W7,
                                 (float*)(ws + o_c1), (float*)(ws + o_c3),
                                 (unsigned short*)(ws + o_fragMt),
                                 (unsigned short*)(ws + o_fragC2),
                                 (unsigned short*)(ws + o_fragCmp),
                                 (float*)(ws + o_W7t));

  int gN4 = (N + 3) / 4;
  int gNode = (Nw + 127) / 128;
  for (int t = 0; t < T; ++t) {
    if (t > 0)
      k_agg<<<gN4, 256, 0, stream>>>((int*)(ws + o_beg_in), (int*)(ws + o_end_in),
                                     (int*)(ws + o_col_in),
                                     (int*)(ws + o_beg_out), (int*)(ws + o_end_out),
                                     (int*)(ws + o_col_out),
                                     (unsigned short*)(ws + o_mub),
                                     (unsigned short*)(ws + o_aggb_in),
                                     (unsigned short*)(ws + o_aggb_out), N);
    k_node<<<gNode, 256, 0, stream>>>(x, (float*)(ws + o_sw_in), (float*)(ws + o_sw_out),
                                      (unsigned short*)(ws + o_aggb_in),
                                      (unsigned short*)(ws + o_aggb_out),
                                      (float*)(ws + o_c1), (float*)(ws + o_c3),
                                      (unsigned short*)(ws + o_fragMt),
                                      (unsigned short*)(ws + o_fragC2),
                                      (unsigned short*)(ws + o_fragCmp),
                                      (float*)(ws + o_mu),
                                      (unsigned short*)(ws + o_mub),
                                      N, t, t > 0 ? 1 : 0, t == T - 1 ? 1 : 0);
  }
  int gPool = ((N + 63) / 64 + 3) / 4;
  k_pool<<<gPool, 256, 0, stream>>>((float*)(ws + o_mu), batch, (float*)(ws + o_pool), N);
  k_poolw6<<<16, 256, 0, stream>>>((float*)(ws + o_pool), W6, (float*)(ws + o_poolw6));
  k_final<<<gN4, 256, 0, stream>>>((float*)(ws + o_mu), batch, (float*)(ws + o_poolw6),
                                   (float*)(ws + o_W7t), W5, out, N);
}